// Round 3
// baseline (247.111 us; speedup 1.0000x reference)
//
#include <hip/hip_runtime.h>
#include <hip/hip_bf16.h>
#include <stdint.h>

typedef __bf16 bf16_t;
typedef bf16_t bf16x8 __attribute__((ext_vector_type(8)));
typedef bf16_t bf16x4 __attribute__((ext_vector_type(4)));
typedef float  f32x4  __attribute__((ext_vector_type(4)));

#define E_DIM 1024
#define B_ROWS 16384

__device__ __forceinline__ void gload_lds16(const void* g, void* l) {
    __builtin_amdgcn_global_load_lds(
        (const __attribute__((address_space(1))) void*)g,
        (__attribute__((address_space(3))) void*)l,
        16, 0, 0);
}

// ---------------------------------------------------------------------------
// merged bias: beff[sel][i] = sum_j Wo_sel[i][j] * bv_sel[j] + bo_sel[i]
// grid = 2048 (sel = blockIdx>>10, i = blockIdx&1023), 64 threads
// ---------------------------------------------------------------------------
__global__ void fuse_bias2_k(const float* __restrict__ Wo_a, const float* __restrict__ bqkv_a,
                             const float* __restrict__ bo_a,
                             const float* __restrict__ Wo_b, const float* __restrict__ bqkv_b,
                             const float* __restrict__ bo_b, float* __restrict__ beff) {
    int idx = blockIdx.x;
    int sel = idx >> 10;
    int i = idx & 1023;
    const float* Wo = sel ? Wo_b : Wo_a;
    const float* bv = (sel ? bqkv_b : bqkv_a) + 2 * E_DIM;
    const float* bo = sel ? bo_b : bo_a;
    float s = 0.f;
    for (int j = threadIdx.x; j < E_DIM; j += 64)
        s += Wo[(size_t)i * E_DIM + j] * bv[j];
#pragma unroll
    for (int o = 32; o > 0; o >>= 1) s += __shfl_down(s, o);
    if (threadIdx.x == 0) beff[sel * E_DIM + i] = s + bo[i];
}

// ---------------------------------------------------------------------------
// Fusion GEMM from f32 inputs: Weff[ms][i][c] = sum_j Wo[i][j] * Wv[j][c]
// Wv = Wqkv + 2*E*E (row-major [j][c]). A reg-staged (straight), B reg-staged
// (transposed scatter into LDS). T14 prefetch. 128x128 tile, BK=64, 4 waves.
// grid = 128 (2 matrices x 8 x 8).
// ---------------------------------------------------------------------------
__global__ __launch_bounds__(256, 1) void fuse_gemm_f32_k(const float* __restrict__ Wqkv_a,
                                                          const float* __restrict__ Wo_a,
                                                          const float* __restrict__ Wqkv_b,
                                                          const float* __restrict__ Wo_b,
                                                          bf16_t* __restrict__ Weff) {
    const size_t MAT = (size_t)E_DIM * E_DIM;
    int bid = blockIdx.x;
    int ms = bid >> 6;
    int t  = bid & 63;
    int mt = t >> 3, nt2 = t & 7;
    const float* Wo = ms ? Wo_b : Wo_a;
    const float* Wv = (ms ? Wqkv_b : Wqkv_a) + 2 * MAT;
    bf16_t* C = Weff + (size_t)ms * MAT;
    int m0 = mt * 128, n0 = nt2 * 128;

    __shared__ __align__(16) bf16_t As[128][64];
    __shared__ __align__(16) bf16_t Bs[128][64];

    int tid = threadIdx.x;
    int lane = tid & 63;
    int wid = tid >> 6;
    int wrow = (wid >> 1) * 64;
    int wcol = (wid & 1) * 64;
    int cl = lane & 15;
    int rg = lane >> 4;

    // A staging coords: row ar, k-half ah
    int ar = tid >> 1, ah = tid & 1;
    const float* aptr = Wo + (size_t)(m0 + ar) * E_DIM + ah * 32;
    // B staging coords: j-row jr, c-quarter cq
    int jr = tid >> 2, cq = tid & 3;
    const float* bptr = Wv + (size_t)jr * E_DIM + n0 + cq * 32;

    f32x4 acc[4][4] = {};
    f32x4 pa[8], pb[8];

    // prologue: prefetch + write tile 0
#pragma unroll
    for (int q = 0; q < 8; ++q) pa[q] = *(const f32x4*)(aptr + 4 * q);
#pragma unroll
    for (int w = 0; w < 8; ++w) pb[w] = *(const f32x4*)(bptr + 4 * w);
#pragma unroll
    for (int q = 0; q < 4; ++q) {
        f32x4 lo = pa[2 * q], hi = pa[2 * q + 1];
        bf16x8 v;
        v[0] = (bf16_t)lo[0]; v[1] = (bf16_t)lo[1]; v[2] = (bf16_t)lo[2]; v[3] = (bf16_t)lo[3];
        v[4] = (bf16_t)hi[0]; v[5] = (bf16_t)hi[1]; v[6] = (bf16_t)hi[2]; v[7] = (bf16_t)hi[3];
        *(bf16x8*)(&As[ar][ah * 32 + q * 8]) = v;
    }
#pragma unroll
    for (int w = 0; w < 8; ++w) {
        f32x4 v = pb[w];
#pragma unroll
        for (int e = 0; e < 4; ++e) Bs[cq * 32 + w * 4 + e][jr] = (bf16_t)v[e];
    }
    __syncthreads();

    for (int kt = 0; kt < 16; ++kt) {
        if (kt + 1 < 16) {
            const float* pA = aptr + (kt + 1) * 64;
            const float* pB = bptr + (size_t)(kt + 1) * 64 * E_DIM;
#pragma unroll
            for (int q = 0; q < 8; ++q) pa[q] = *(const f32x4*)(pA + 4 * q);
#pragma unroll
            for (int w = 0; w < 8; ++w) pb[w] = *(const f32x4*)(pB + 4 * w);
        }
#pragma unroll
        for (int ks = 0; ks < 2; ++ks) {
            int kk = ks * 32 + rg * 8;
            bf16x8 af[4], bq[4];
#pragma unroll
            for (int m = 0; m < 4; ++m) af[m] = *(const bf16x8*)(&As[wrow + m * 16 + cl][kk]);
#pragma unroll
            for (int n = 0; n < 4; ++n) bq[n] = *(const bf16x8*)(&Bs[wcol + n * 16 + cl][kk]);
#pragma unroll
            for (int m = 0; m < 4; ++m)
#pragma unroll
                for (int n = 0; n < 4; ++n)
                    acc[m][n] = __builtin_amdgcn_mfma_f32_16x16x32_bf16(af[m], bq[n], acc[m][n], 0, 0, 0);
        }
        __syncthreads();
        if (kt + 1 < 16) {
#pragma unroll
            for (int q = 0; q < 4; ++q) {
                f32x4 lo = pa[2 * q], hi = pa[2 * q + 1];
                bf16x8 v;
                v[0] = (bf16_t)lo[0]; v[1] = (bf16_t)lo[1]; v[2] = (bf16_t)lo[2]; v[3] = (bf16_t)lo[3];
                v[4] = (bf16_t)hi[0]; v[5] = (bf16_t)hi[1]; v[6] = (bf16_t)hi[2]; v[7] = (bf16_t)hi[3];
                *(bf16x8*)(&As[ar][ah * 32 + q * 8]) = v;
            }
#pragma unroll
            for (int w = 0; w < 8; ++w) {
                f32x4 v = pb[w];
#pragma unroll
                for (int e = 0; e < 4; ++e) Bs[cq * 32 + w * 4 + e][jr] = (bf16_t)v[e];
            }
            __syncthreads();
        }
    }

#pragma unroll
    for (int m = 0; m < 4; ++m) {
        int r = m0 + wrow + m * 16 + rg * 4;
#pragma unroll
        for (int n = 0; n < 4; ++n) {
            int c = n0 + wcol + n * 16 + cl;
#pragma unroll
            for (int j = 0; j < 4; ++j)
                C[(size_t)(r + j) * E_DIM + c] = (bf16_t)acc[m][n][j];
        }
    }
}

// ---------------------------------------------------------------------------
// Main GEMM, f32 A fused cvt (T14 prefetch), B bf16 via global_load_lds.
// out[b][sel*1024+n] = sum_k X[b][k] * Weff[sel][n][k] + beff[sel][n]
// 128x128 tile, BK=64, 4 waves, grid = 2048, XCD-swizzled, mt-major chunks.
// ---------------------------------------------------------------------------
__global__ __launch_bounds__(256, 2) void main_gemm_f32a_k(const float* __restrict__ text,
                                                           const float* __restrict__ ecg,
                                                           const bf16_t* __restrict__ Weff,
                                                           const float* __restrict__ beff,
                                                           float* __restrict__ out) {
    int bid = blockIdx.x;
    // bijective XCD swizzle: nwg = 2048, 2048 % 8 == 0
    int wg = (bid & 7) * 256 + (bid >> 3);
    int nt = wg & 15;   // 16 col tiles (8 per matrix)
    int mt = wg >> 4;   // 128 row tiles
    int sel = nt >> 3;
    const float*  A = sel ? text : ecg;
    const bf16_t* W = Weff + (size_t)sel * E_DIM * E_DIM;
    const float* bb = beff + sel * E_DIM;
    int n0 = (nt & 7) * 128;
    int m0 = mt * 128;

    __shared__ __align__(16) bf16_t As[128][64];
    __shared__ __align__(16) bf16_t Bs[128][64];

    int tid = threadIdx.x;
    int lane = tid & 63;
    int wid = tid >> 6;
    int wrow = (wid >> 1) * 64;
    int wcol = (wid & 1) * 64;
    int cl = lane & 15;
    int rg = lane >> 4;

    // A staging coords: row ar (0..127), k-half ah
    int ar = tid >> 1, ah = tid & 1;
    const float* aptr = A + (size_t)(m0 + ar) * E_DIM + ah * 32;

    f32x4 acc[4][4] = {};
    f32x4 pa[8];

    // ---- prologue: tile 0 ----
#pragma unroll
    for (int q = 0; q < 8; ++q) pa[q] = *(const f32x4*)(aptr + 4 * q);
#pragma unroll
    for (int i = 0; i < 4; ++i) {
        int chunk = i * 256 + wid * 64 + lane;
        int brow = chunk >> 3;
        int bk = (chunk & 7) * 8;
        char* lb = (char*)(&Bs[0][0]) + (size_t)(i * 256 + wid * 64) * 16;
        gload_lds16(W + (size_t)(n0 + brow) * E_DIM + bk, lb);
    }
#pragma unroll
    for (int q = 0; q < 4; ++q) {
        f32x4 lo = pa[2 * q], hi = pa[2 * q + 1];
        bf16x8 v;
        v[0] = (bf16_t)lo[0]; v[1] = (bf16_t)lo[1]; v[2] = (bf16_t)lo[2]; v[3] = (bf16_t)lo[3];
        v[4] = (bf16_t)hi[0]; v[5] = (bf16_t)hi[1]; v[6] = (bf16_t)hi[2]; v[7] = (bf16_t)hi[3];
        *(bf16x8*)(&As[ar][ah * 32 + q * 8]) = v;
    }
    __syncthreads();

    for (int kt = 0; kt < 16; ++kt) {
        // T14: issue next A tile's f32 loads before compute (fly across MFMA)
        if (kt + 1 < 16) {
            const float* p = aptr + (kt + 1) * 64;
#pragma unroll
            for (int q = 0; q < 8; ++q) pa[q] = *(const f32x4*)(p + 4 * q);
        }
#pragma unroll
        for (int ks = 0; ks < 2; ++ks) {
            int kk = ks * 32 + rg * 8;
            bf16x8 af[4], bq[4];
#pragma unroll
            for (int m = 0; m < 4; ++m) af[m] = *(const bf16x8*)(&As[wrow + m * 16 + cl][kk]);
#pragma unroll
            for (int n = 0; n < 4; ++n) bq[n] = *(const bf16x8*)(&Bs[wcol + n * 16 + cl][kk]);
#pragma unroll
            for (int m = 0; m < 4; ++m)
#pragma unroll
                for (int n = 0; n < 4; ++n)
                    acc[m][n] = __builtin_amdgcn_mfma_f32_16x16x32_bf16(af[m], bq[n], acc[m][n], 0, 0, 0);
        }
        __syncthreads();   // readers of tile kt done; pa landed
        if (kt + 1 < 16) {
            // cvt + ds_write A(kt+1)
#pragma unroll
            for (int q = 0; q < 4; ++q) {
                f32x4 lo = pa[2 * q], hi = pa[2 * q + 1];
                bf16x8 v;
                v[0] = (bf16_t)lo[0]; v[1] = (bf16_t)lo[1]; v[2] = (bf16_t)lo[2]; v[3] = (bf16_t)lo[3];
                v[4] = (bf16_t)hi[0]; v[5] = (bf16_t)hi[1]; v[6] = (bf16_t)hi[2]; v[7] = (bf16_t)hi[3];
                *(bf16x8*)(&As[ar][ah * 32 + q * 8]) = v;
            }
            // issue B(kt+1)
#pragma unroll
            for (int i = 0; i < 4; ++i) {
                int chunk = i * 256 + wid * 64 + lane;
                int brow = chunk >> 3;
                int bk = (chunk & 7) * 8;
                char* lb = (char*)(&Bs[0][0]) + (size_t)(i * 256 + wid * 64) * 16;
                gload_lds16(W + (size_t)(n0 + brow) * E_DIM + (kt + 1) * 64 + bk, lb);
            }
            __syncthreads();   // A writes visible, B(kt+1) drained
        }
    }

    // epilogue: +bias, f32 store (out width = 2048)
#pragma unroll
    for (int n = 0; n < 4; ++n) {
        int ch = n0 + wcol + n * 16 + cl;
        float bias = bb[ch];
        size_t gc = (size_t)sel * E_DIM + ch;
#pragma unroll
        for (int m = 0; m < 4; ++m) {
            int r = m0 + wrow + m * 16 + rg * 4;
#pragma unroll
            for (int j = 0; j < 4; ++j)
                out[(size_t)(r + j) * (2 * E_DIM) + gc] = acc[m][n][j] + bias;
        }
    }
}

// ---------------------------------------------------------------------------
extern "C" void kernel_launch(void* const* d_in, const int* in_sizes, int n_in,
                              void* d_out, int out_size, void* d_ws, size_t ws_size,
                              hipStream_t stream) {
    const float* text   = (const float*)d_in[0];
    const float* ecg    = (const float*)d_in[1];
    const float* Wqkv_a = (const float*)d_in[7];
    const float* bqkv_a = (const float*)d_in[8];
    const float* Wo_a   = (const float*)d_in[9];
    const float* bo_a   = (const float*)d_in[10];
    const float* Wqkv_b = (const float*)d_in[11];
    const float* bqkv_b = (const float*)d_in[12];
    const float* Wo_b   = (const float*)d_in[13];
    const float* bo_b   = (const float*)d_in[14];

    const size_t MAT = (size_t)E_DIM * E_DIM;
    bf16_t* Weff = (bf16_t*)d_ws;               // 2 * 2MB
    float*  beff = (float*)(Weff + 2 * MAT);    // 2 * 4KB

    fuse_gemm_f32_k<<<128, 256, 0, stream>>>(Wqkv_a, Wo_a, Wqkv_b, Wo_b, Weff);
    fuse_bias2_k<<<2048, 64, 0, stream>>>(Wo_a, bqkv_a, bo_a, Wo_b, bqkv_b, bo_b, beff);
    main_gemm_f32a_k<<<2048, 256, 0, stream>>>(text, ecg, Weff, beff, (float*)d_out);
}

// Round 4
// 196.688 us; speedup vs baseline: 1.2564x; 1.2564x over previous
//
#include <hip/hip_runtime.h>
#include <hip/hip_bf16.h>
#include <stdint.h>

typedef __bf16 bf16_t;
typedef bf16_t bf16x8 __attribute__((ext_vector_type(8)));
typedef bf16_t bf16x4 __attribute__((ext_vector_type(4)));
typedef float  f32x4  __attribute__((ext_vector_type(4)));

#define E_DIM 1024
#define B_ROWS 16384

__device__ __forceinline__ void gload_lds16(const void* g, void* l) {
    __builtin_amdgcn_global_load_lds(
        (const __attribute__((address_space(1))) void*)g,
        (__attribute__((address_space(3))) void*)l,
        16, 0, 0);
}

// ---------------------------------------------------------------------------
// merged X convert: ecg -> Xb[0..XMAT), text -> Xb[XMAT..2*XMAT)  (f32->bf16)
// ---------------------------------------------------------------------------
__global__ __launch_bounds__(256) void cvt_x2_k(const float* __restrict__ ecg,
                                                const float* __restrict__ text,
                                                bf16_t* __restrict__ out) {
    const int half = (B_ROWS * E_DIM) / 8;     // chunks per matrix
    const int total = 2 * half;
    int stride = gridDim.x * blockDim.x;
    for (int i = blockIdx.x * blockDim.x + threadIdx.x; i < total; i += stride) {
        const float* src = (i < half) ? ecg : text;
        int j = (i < half) ? i : i - half;
        f32x4 lo = ((const f32x4*)src)[2 * j];
        f32x4 hi = ((const f32x4*)src)[2 * j + 1];
        bf16x8 v;
        v[0] = (bf16_t)lo[0]; v[1] = (bf16_t)lo[1]; v[2] = (bf16_t)lo[2]; v[3] = (bf16_t)lo[3];
        v[4] = (bf16_t)hi[0]; v[5] = (bf16_t)hi[1]; v[6] = (bf16_t)hi[2]; v[7] = (bf16_t)hi[3];
        ((bf16x8*)out)[i] = v;
    }
}

// ---------------------------------------------------------------------------
// merged bias: beff[sel][i] = sum_j Wo_sel[i][j] * bv_sel[j] + bo_sel[i]
// (R3-proven)
// ---------------------------------------------------------------------------
__global__ void fuse_bias2_k(const float* __restrict__ Wo_a, const float* __restrict__ bqkv_a,
                             const float* __restrict__ bo_a,
                             const float* __restrict__ Wo_b, const float* __restrict__ bqkv_b,
                             const float* __restrict__ bo_b, float* __restrict__ beff) {
    int idx = blockIdx.x;
    int sel = idx >> 10;
    int i = idx & 1023;
    const float* Wo = sel ? Wo_b : Wo_a;
    const float* bv = (sel ? bqkv_b : bqkv_a) + 2 * E_DIM;
    const float* bo = sel ? bo_b : bo_a;
    float s = 0.f;
    for (int j = threadIdx.x; j < E_DIM; j += 64)
        s += Wo[(size_t)i * E_DIM + j] * bv[j];
#pragma unroll
    for (int o = 32; o > 0; o >>= 1) s += __shfl_down(s, o);
    if (threadIdx.x == 0) beff[sel * E_DIM + i] = s + bo[i];
}

// ---------------------------------------------------------------------------
// Fusion GEMM from f32 inputs (R3-proven): Weff[ms][i][c] = sum_j Wo[i][j]*Wv[j][c]
// ---------------------------------------------------------------------------
__global__ __launch_bounds__(256, 1) void fuse_gemm_f32_k(const float* __restrict__ Wqkv_a,
                                                          const float* __restrict__ Wo_a,
                                                          const float* __restrict__ Wqkv_b,
                                                          const float* __restrict__ Wo_b,
                                                          bf16_t* __restrict__ Weff) {
    const size_t MAT = (size_t)E_DIM * E_DIM;
    int bid = blockIdx.x;
    int ms = bid >> 6;
    int t  = bid & 63;
    int mt = t >> 3, nt2 = t & 7;
    const float* Wo = ms ? Wo_b : Wo_a;
    const float* Wv = (ms ? Wqkv_b : Wqkv_a) + 2 * MAT;
    bf16_t* C = Weff + (size_t)ms * MAT;
    int m0 = mt * 128, n0 = nt2 * 128;

    __shared__ __align__(16) bf16_t As[128][64];
    __shared__ __align__(16) bf16_t Bs[128][64];

    int tid = threadIdx.x;
    int lane = tid & 63;
    int wid = tid >> 6;
    int wrow = (wid >> 1) * 64;
    int wcol = (wid & 1) * 64;
    int cl = lane & 15;
    int rg = lane >> 4;

    int ar = tid >> 1, ah = tid & 1;
    const float* aptr = Wo + (size_t)(m0 + ar) * E_DIM + ah * 32;
    int jr = tid >> 2, cq = tid & 3;
    const float* bptr = Wv + (size_t)jr * E_DIM + n0 + cq * 32;

    f32x4 acc[4][4] = {};
    f32x4 pa[8], pb[8];

#pragma unroll
    for (int q = 0; q < 8; ++q) pa[q] = *(const f32x4*)(aptr + 4 * q);
#pragma unroll
    for (int w = 0; w < 8; ++w) pb[w] = *(const f32x4*)(bptr + 4 * w);
#pragma unroll
    for (int q = 0; q < 4; ++q) {
        f32x4 lo = pa[2 * q], hi = pa[2 * q + 1];
        bf16x8 v;
        v[0] = (bf16_t)lo[0]; v[1] = (bf16_t)lo[1]; v[2] = (bf16_t)lo[2]; v[3] = (bf16_t)lo[3];
        v[4] = (bf16_t)hi[0]; v[5] = (bf16_t)hi[1]; v[6] = (bf16_t)hi[2]; v[7] = (bf16_t)hi[3];
        *(bf16x8*)(&As[ar][ah * 32 + q * 8]) = v;
    }
#pragma unroll
    for (int w = 0; w < 8; ++w) {
        f32x4 v = pb[w];
#pragma unroll
        for (int e = 0; e < 4; ++e) Bs[cq * 32 + w * 4 + e][jr] = (bf16_t)v[e];
    }
    __syncthreads();

    for (int kt = 0; kt < 16; ++kt) {
        if (kt + 1 < 16) {
            const float* pA = aptr + (kt + 1) * 64;
            const float* pB = bptr + (size_t)(kt + 1) * 64 * E_DIM;
#pragma unroll
            for (int q = 0; q < 8; ++q) pa[q] = *(const f32x4*)(pA + 4 * q);
#pragma unroll
            for (int w = 0; w < 8; ++w) pb[w] = *(const f32x4*)(pB + 4 * w);
        }
#pragma unroll
        for (int ks = 0; ks < 2; ++ks) {
            int kk = ks * 32 + rg * 8;
            bf16x8 af[4], bq[4];
#pragma unroll
            for (int m = 0; m < 4; ++m) af[m] = *(const bf16x8*)(&As[wrow + m * 16 + cl][kk]);
#pragma unroll
            for (int n = 0; n < 4; ++n) bq[n] = *(const bf16x8*)(&Bs[wcol + n * 16 + cl][kk]);
#pragma unroll
            for (int m = 0; m < 4; ++m)
#pragma unroll
                for (int n = 0; n < 4; ++n)
                    acc[m][n] = __builtin_amdgcn_mfma_f32_16x16x32_bf16(af[m], bq[n], acc[m][n], 0, 0, 0);
        }
        __syncthreads();
        if (kt + 1 < 16) {
#pragma unroll
            for (int q = 0; q < 4; ++q) {
                f32x4 lo = pa[2 * q], hi = pa[2 * q + 1];
                bf16x8 v;
                v[0] = (bf16_t)lo[0]; v[1] = (bf16_t)lo[1]; v[2] = (bf16_t)lo[2]; v[3] = (bf16_t)lo[3];
                v[4] = (bf16_t)hi[0]; v[5] = (bf16_t)hi[1]; v[6] = (bf16_t)hi[2]; v[7] = (bf16_t)hi[3];
                *(bf16x8*)(&As[ar][ah * 32 + q * 8]) = v;
            }
#pragma unroll
            for (int w = 0; w < 8; ++w) {
                f32x4 v = pb[w];
#pragma unroll
                for (int e = 0; e < 4; ++e) Bs[cq * 32 + w * 4 + e][jr] = (bf16_t)v[e];
            }
            __syncthreads();
        }
    }

#pragma unroll
    for (int m = 0; m < 4; ++m) {
        int r = m0 + wrow + m * 16 + rg * 4;
#pragma unroll
        for (int n = 0; n < 4; ++n) {
            int c = n0 + wcol + n * 16 + cl;
#pragma unroll
            for (int j = 0; j < 4; ++j)
                C[(size_t)(r + j) * E_DIM + c] = (bf16_t)acc[m][n][j];
        }
    }
}

// ---------------------------------------------------------------------------
// Main GEMM — 256x128 tile, BK=64, 8 waves (4Mx2N), triple-buffered LDS,
// staged 2 K-tiles ahead via global_load_lds, counted vmcnt(6) boundaries,
// XOR-swizzled LDS reads (conflict-free), setprio around MFMA clusters.
// grid = 1024 (64 mt x 16 nt), XCD-swizzled.
// ---------------------------------------------------------------------------
__global__ __launch_bounds__(512, 2) void main_gemm_8ph_k(const bf16_t* __restrict__ Xb,
                                                          const bf16_t* __restrict__ Weff,
                                                          const float* __restrict__ beff,
                                                          float* __restrict__ out) {
    const size_t MAT  = (size_t)E_DIM * E_DIM;
    const size_t XMAT = (size_t)B_ROWS * E_DIM;

    int bid = blockIdx.x;
    // bijective XCD swizzle: nwg = 1024, 1024 % 8 == 0; nt-fastest within XCD chunk
    int wg = (bid & 7) * 128 + (bid >> 3);
    int nt = wg & 15;          // 16 col tiles (8 per matrix)
    int mt = wg >> 4;          // 64 row tiles
    int sel = nt >> 3;
    int n0 = (nt & 7) * 128;
    int m0 = mt * 256;

    const bf16_t* gA = Xb + (size_t)sel * XMAT + (size_t)m0 * E_DIM;
    const bf16_t* gB = Weff + (size_t)sel * MAT + (size_t)n0 * E_DIM;
    const float*  bb = beff + sel * E_DIM;

    // 3-deep buffers: A 256x64 bf16 (32KB) x3, B 128x64 bf16 (16KB) x3 = 144KB
    __shared__ __align__(16) bf16_t sA0[256 * 64], sA1[256 * 64], sA2[256 * 64];
    __shared__ __align__(16) bf16_t sB0[128 * 64], sB1[128 * 64], sB2[128 * 64];
    bf16_t* const sAb[3] = {sA0, sA1, sA2};
    bf16_t* const sBb[3] = {sB0, sB1, sB2};

    int tid  = threadIdx.x;
    int lane = tid & 63;
    int wid  = tid >> 6;        // 8 waves: 4M x 2N
    int wrow = (wid >> 1) * 64; // 0,64,128,192
    int wcol = (wid & 1) * 64;  // 0,64
    int cl = lane & 15;
    int rg = lane >> 4;

    // staging precompute: A = 4 block-wide loads, B = 2; 16B/lane each.
    // LDS dest linear (chunk c -> bytes [c*16, c*16+16)); global source
    // pre-swizzled: col ^= (row&7)<<3 elements (involution, 16B-granular).
    int goA[4], ldA[4], goB[2], ldB[2];
#pragma unroll
    for (int l = 0; l < 4; ++l) {
        int c = l * 512 + tid;
        int row = c >> 3;
        int col = (c & 7) * 8;
        int scol = col ^ ((row & 7) << 3);
        goA[l] = row * E_DIM + scol;
        ldA[l] = c * 8;
    }
#pragma unroll
    for (int l = 0; l < 2; ++l) {
        int c = l * 512 + tid;
        int row = c >> 3;
        int col = (c & 7) * 8;
        int scol = col ^ ((row & 7) << 3);
        goB[l] = row * E_DIM + scol;
        ldB[l] = c * 8;
    }

    // fragment read offsets (elements), swizzled to match staging
    int aoff[2][4], boff[2][4];
#pragma unroll
    for (int ks = 0; ks < 2; ++ks) {
#pragma unroll
        for (int m = 0; m < 4; ++m) {
            int ra = wrow + m * 16 + cl;
            aoff[ks][m] = ra * 64 + ((ks * 32 + rg * 8) ^ ((ra & 7) << 3));
            int rb = wcol + m * 16 + cl;
            boff[ks][m] = rb * 64 + ((ks * 32 + rg * 8) ^ ((rb & 7) << 3));
        }
    }

    f32x4 acc[4][4] = {};

    // prologue: stage tile 0 -> buf0, tile 1 -> buf1 (6 loads each)
#pragma unroll
    for (int l = 0; l < 4; ++l) gload_lds16(gA + goA[l], sA0 + ldA[l]);
#pragma unroll
    for (int l = 0; l < 2; ++l) gload_lds16(gB + goB[l], sB0 + ldB[l]);
#pragma unroll
    for (int l = 0; l < 4; ++l) gload_lds16(gA + 64 + goA[l], sA1 + ldA[l]);
#pragma unroll
    for (int l = 0; l < 2; ++l) gload_lds16(gB + 64 + goB[l], sB1 + ldB[l]);
    asm volatile("s_waitcnt vmcnt(6)" ::: "memory");   // tile 0 landed, tile 1 in flight
    __builtin_amdgcn_s_barrier();

#pragma unroll
    for (int t = 0; t < 16; ++t) {
        bf16_t* cA = sAb[t % 3];
        bf16_t* cB = sBb[t % 3];
        bf16_t* nA = sAb[(t + 2) % 3];
        bf16_t* nB = sBb[(t + 2) % 3];
#pragma unroll
        for (int ks = 0; ks < 2; ++ks) {
            bf16x8 af[4], bq[4];
#pragma unroll
            for (int m = 0; m < 4; ++m) af[m] = *(const bf16x8*)(cA + aoff[ks][m]);
#pragma unroll
            for (int n = 0; n < 4; ++n) bq[n] = *(const bf16x8*)(cB + boff[ks][n]);
            if (t + 2 < 16) {
                int kt = t + 2;
                if (ks == 0) {
                    gload_lds16(gA + kt * 64 + goA[0], nA + ldA[0]);
                    gload_lds16(gA + kt * 64 + goA[1], nA + ldA[1]);
                    gload_lds16(gA + kt * 64 + goA[2], nA + ldA[2]);
                } else {
                    gload_lds16(gA + kt * 64 + goA[3], nA + ldA[3]);
                    gload_lds16(gB + kt * 64 + goB[0], nB + ldB[0]);
                    gload_lds16(gB + kt * 64 + goB[1], nB + ldB[1]);
                }
            }
            __builtin_amdgcn_s_barrier();
            __builtin_amdgcn_s_setprio(1);
#pragma unroll
            for (int m = 0; m < 4; ++m)
#pragma unroll
                for (int n = 0; n < 4; ++n)
                    acc[m][n] = __builtin_amdgcn_mfma_f32_16x16x32_bf16(af[m], bq[n], acc[m][n], 0, 0, 0);
            __builtin_amdgcn_s_setprio(0);
            if (ks == 1) {
                // boundary: guarantee tile t+1 fully in LDS; keep t+2 in flight
                if (t < 14)       asm volatile("s_waitcnt vmcnt(6)" ::: "memory");
                else if (t == 14) asm volatile("s_waitcnt vmcnt(0)" ::: "memory");
            }
            __builtin_amdgcn_s_barrier();
        }
    }

    // epilogue: +bias, f32 store (out width = 2048)
#pragma unroll
    for (int n = 0; n < 4; ++n) {
        int ch = n0 + wcol + n * 16 + cl;
        float bias = bb[ch];
        size_t gc = (size_t)sel * E_DIM + ch;
#pragma unroll
        for (int m = 0; m < 4; ++m) {
            int r = m0 + wrow + m * 16 + rg * 4;
#pragma unroll
            for (int j = 0; j < 4; ++j)
                out[(size_t)(r + j) * (2 * E_DIM) + gc] = acc[m][n][j] + bias;
        }
    }
}

// ---------------------------------------------------------------------------
extern "C" void kernel_launch(void* const* d_in, const int* in_sizes, int n_in,
                              void* d_out, int out_size, void* d_ws, size_t ws_size,
                              hipStream_t stream) {
    const float* text   = (const float*)d_in[0];
    const float* ecg    = (const float*)d_in[1];
    const float* Wqkv_a = (const float*)d_in[7];
    const float* bqkv_a = (const float*)d_in[8];
    const float* Wo_a   = (const float*)d_in[9];
    const float* bo_a   = (const float*)d_in[10];
    const float* Wqkv_b = (const float*)d_in[11];
    const float* bqkv_b = (const float*)d_in[12];
    const float* Wo_b   = (const float*)d_in[13];
    const float* bo_b   = (const float*)d_in[14];

    const size_t MAT  = (size_t)E_DIM * E_DIM;
    const size_t XMAT = (size_t)B_ROWS * E_DIM;
    bf16_t* Weff = (bf16_t*)d_ws;                 // 4 MB
    float*  beff = (float*)(Weff + 2 * MAT);      // 8 KB
    bf16_t* Xb   = (bf16_t*)(beff + 2 * E_DIM);   // 64 MB

    cvt_x2_k<<<2048, 256, 0, stream>>>(ecg, text, Xb);
    fuse_gemm_f32_k<<<128, 256, 0, stream>>>(Wqkv_a, Wo_a, Wqkv_b, Wo_b, Weff);
    fuse_bias2_k<<<2048, 64, 0, stream>>>(Wo_a, bqkv_a, bo_a, Wo_b, bqkv_b, bo_b, beff);
    main_gemm_8ph_k<<<1024, 512, 0, stream>>>(Xb, Weff, beff, (float*)d_out);
}

// Round 5
// 158.471 us; speedup vs baseline: 1.5593x; 1.2412x over previous
//
#include <hip/hip_runtime.h>
#include <hip/hip_bf16.h>
#include <stdint.h>

typedef __bf16 bf16_t;
typedef bf16_t bf16x8 __attribute__((ext_vector_type(8)));
typedef bf16_t bf16x4 __attribute__((ext_vector_type(4)));
typedef float  f32x4  __attribute__((ext_vector_type(4)));

#define E_DIM 1024
#define B_ROWS 16384

__device__ __forceinline__ void gload_lds16(const void* g, void* l) {
    __builtin_amdgcn_global_load_lds(
        (const __attribute__((address_space(1))) void*)g,
        (__attribute__((address_space(3))) void*)l,
        16, 0, 0);
}

// ---------------------------------------------------------------------------
// Wo_a,Wo_b -> bf16 (one launch). grid 2048 x 256, i covers 2*MAT/4 chunks.
// ---------------------------------------------------------------------------
__global__ __launch_bounds__(256) void cvt_w2_k(const float* __restrict__ Wo_a,
                                                const float* __restrict__ Wo_b,
                                                bf16_t* __restrict__ out) {
    const int n4 = (E_DIM * E_DIM) / 4;
    int i = blockIdx.x * blockDim.x + threadIdx.x;
    const float* src = (i < n4) ? Wo_a : Wo_b;
    int j = (i < n4) ? i : i - n4;
    f32x4 v = ((const f32x4*)src)[j];
    bf16x4 o;
    o[0] = (bf16_t)v[0]; o[1] = (bf16_t)v[1];
    o[2] = (bf16_t)v[2]; o[3] = (bf16_t)v[3];
    ((bf16x4*)out)[i] = o;
}

// ---------------------------------------------------------------------------
// transposed cvt for both Wv: out[k][j] = in[j][k] (1024x1024 each). grid 512.
// ---------------------------------------------------------------------------
__global__ __launch_bounds__(256) void transpose_cvt2_k(const float* __restrict__ Wqkv_a,
                                                        const float* __restrict__ Wqkv_b,
                                                        bf16_t* __restrict__ out) {
    const size_t MAT = (size_t)E_DIM * E_DIM;
    int b = blockIdx.x;
    int ms = b >> 8;
    const float* in = (ms ? Wqkv_b : Wqkv_a) + 2 * MAT;
    bf16_t* o = out + (size_t)ms * MAT;
    int bb = b & 255;
    __shared__ float t[64][65];
    int bx = bb & 15;   // k tile
    int by = bb >> 4;   // j tile
    int j0 = by * 64, k0 = bx * 64;
    int tid = threadIdx.x;
#pragma unroll
    for (int p = 0; p < 4; ++p) {
        int u = tid + 256 * p;
        int r = u >> 4, c4 = u & 15;
        f32x4 v = *(const f32x4*)(in + (size_t)(j0 + r) * E_DIM + k0 + c4 * 4);
        t[r][c4 * 4 + 0] = v[0]; t[r][c4 * 4 + 1] = v[1];
        t[r][c4 * 4 + 2] = v[2]; t[r][c4 * 4 + 3] = v[3];
    }
    __syncthreads();
#pragma unroll
    for (int p = 0; p < 4; ++p) {
        int u = tid + 256 * p;
        int r = u >> 4, c4 = u & 15;
        bf16x4 ov;
        ov[0] = (bf16_t)t[c4 * 4 + 0][r];
        ov[1] = (bf16_t)t[c4 * 4 + 1][r];
        ov[2] = (bf16_t)t[c4 * 4 + 2][r];
        ov[3] = (bf16_t)t[c4 * 4 + 3][r];
        *(bf16x4*)(o + (size_t)(k0 + r) * E_DIM + j0 + c4 * 4) = ov;
    }
}

// ---------------------------------------------------------------------------
// merged bias: beff[sel][i] = sum_j Wo_sel[i][j] * bv_sel[j] + bo_sel[i]
// ---------------------------------------------------------------------------
__global__ void fuse_bias2_k(const float* __restrict__ Wo_a, const float* __restrict__ bqkv_a,
                             const float* __restrict__ bo_a,
                             const float* __restrict__ Wo_b, const float* __restrict__ bqkv_b,
                             const float* __restrict__ bo_b, float* __restrict__ beff) {
    int idx = blockIdx.x;
    int sel = idx >> 10;
    int i = idx & 1023;
    const float* Wo = sel ? Wo_b : Wo_a;
    const float* bv = (sel ? bqkv_b : bqkv_a) + 2 * E_DIM;
    const float* bo = sel ? bo_b : bo_a;
    float s = 0.f;
    for (int j = threadIdx.x; j < E_DIM; j += 64)
        s += Wo[(size_t)i * E_DIM + j] * bv[j];
#pragma unroll
    for (int o = 32; o > 0; o >>= 1) s += __shfl_down(s, o);
    if (threadIdx.x == 0) beff[sel * E_DIM + i] = s + bo[i];
}

// ---------------------------------------------------------------------------
// Fusion GEMM (R2-proven): Weff[i][k] = sum_j WoB[i][j] * WvT[k][j] (NT bf16)
// ---------------------------------------------------------------------------
__global__ __launch_bounds__(256, 2) void fuse_gemm_k(const bf16_t* __restrict__ WoB,
                                                      const bf16_t* __restrict__ WvT,
                                                      bf16_t* __restrict__ Weff) {
    const size_t MAT = (size_t)E_DIM * E_DIM;
    int bid = blockIdx.x;
    int ms = bid >> 6;
    int t  = bid & 63;
    int mt = t >> 3, nt = t & 7;
    const bf16_t* A  = WoB + (size_t)ms * MAT;
    const bf16_t* Bm = WvT + (size_t)ms * MAT;
    bf16_t*       C  = Weff + (size_t)ms * MAT;
    int m0 = mt * 128, n0 = nt * 128;

    __shared__ __align__(16) bf16_t As[128][64];
    __shared__ __align__(16) bf16_t Bs[128][64];

    int tid = threadIdx.x;
    int lane = tid & 63;
    int wid = tid >> 6;
    int wrow = (wid >> 1) * 64;
    int wcol = (wid & 1) * 64;
    int cl = lane & 15;
    int rg = lane >> 4;

    f32x4 acc[4][4] = {};

    for (int kt = 0; kt < 16; ++kt) {
#pragma unroll
        for (int i = 0; i < 4; ++i) {
            int chunk = i * 256 + wid * 64 + lane;
            int row = chunk >> 3;
            int kk8 = (chunk & 7) * 8;
            char* la = (char*)(&As[0][0]) + (size_t)(i * 256 + wid * 64) * 16;
            char* lb = (char*)(&Bs[0][0]) + (size_t)(i * 256 + wid * 64) * 16;
            gload_lds16(A  + (size_t)(m0 + row) * E_DIM + kt * 64 + kk8, la);
            gload_lds16(Bm + (size_t)(n0 + row) * E_DIM + kt * 64 + kk8, lb);
        }
        __syncthreads();
#pragma unroll
        for (int ks = 0; ks < 2; ++ks) {
            int kk = ks * 32 + rg * 8;
            bf16x8 af[4], bq[4];
#pragma unroll
            for (int m = 0; m < 4; ++m) af[m] = *(const bf16x8*)(&As[wrow + m * 16 + cl][kk]);
#pragma unroll
            for (int n = 0; n < 4; ++n) bq[n] = *(const bf16x8*)(&Bs[wcol + n * 16 + cl][kk]);
#pragma unroll
            for (int m = 0; m < 4; ++m)
#pragma unroll
                for (int n = 0; n < 4; ++n)
                    acc[m][n] = __builtin_amdgcn_mfma_f32_16x16x32_bf16(af[m], bq[n], acc[m][n], 0, 0, 0);
        }
        __syncthreads();
    }

#pragma unroll
    for (int m = 0; m < 4; ++m) {
        int r = m0 + wrow + m * 16 + rg * 4;
#pragma unroll
        for (int n = 0; n < 4; ++n) {
            int c = n0 + wcol + n * 16 + cl;
#pragma unroll
            for (int j = 0; j < 4; ++j)
                C[(size_t)(r + j) * E_DIM + c] = (bf16_t)acc[m][n][j];
        }
    }
}

// ---------------------------------------------------------------------------
// big f32 -> bf16 convert of both X matrices
// ---------------------------------------------------------------------------
__global__ __launch_bounds__(256) void cvt_x2_k(const float* __restrict__ ecg,
                                                const float* __restrict__ text,
                                                bf16_t* __restrict__ out) {
    const int half = (B_ROWS * E_DIM) / 8;
    const int total = 2 * half;
    int stride = gridDim.x * blockDim.x;
    for (int i = blockIdx.x * blockDim.x + threadIdx.x; i < total; i += stride) {
        const float* src = (i < half) ? ecg : text;
        int j = (i < half) ? i : i - half;
        f32x4 lo = ((const f32x4*)src)[2 * j];
        f32x4 hi = ((const f32x4*)src)[2 * j + 1];
        bf16x8 v;
        v[0] = (bf16_t)lo[0]; v[1] = (bf16_t)lo[1]; v[2] = (bf16_t)lo[2]; v[3] = (bf16_t)lo[3];
        v[4] = (bf16_t)hi[0]; v[5] = (bf16_t)hi[1]; v[6] = (bf16_t)hi[2]; v[7] = (bf16_t)hi[3];
        ((bf16x8*)out)[i] = v;
    }
}

// ---------------------------------------------------------------------------
// Main GEMM — m201-style 8-phase: 256x256 tile, BK=64, 8 waves with
// interleaved 128x64 per-wave output, double-buffered LDS (128KB),
// half-stage staging 1/phase, per-phase counted vmcnt(4), setprio MFMA.
// grid = 512 (64 mt x 8 nt), XCD-swizzled.
// ---------------------------------------------------------------------------
#define VMW(n) asm volatile("s_waitcnt vmcnt(" #n ")" ::: "memory")
#define BAR()  __builtin_amdgcn_s_barrier()

__global__ __launch_bounds__(512, 2) void main_gemm_256_k(const bf16_t* __restrict__ Xb,
                                                          const bf16_t* __restrict__ Weff,
                                                          const float* __restrict__ beff,
                                                          float* __restrict__ out) {
    const size_t MAT  = (size_t)E_DIM * E_DIM;
    const size_t XMAT = (size_t)B_ROWS * E_DIM;

    int bid = blockIdx.x;
    // bijective XCD swizzle: nwg = 512, 512 % 8 == 0; nt-fastest inside chunk
    int wg = (bid & 7) * 64 + (bid >> 3);
    int nt = wg & 7;          // 8 col tiles (4 per matrix)
    int mt = wg >> 3;         // 64 row tiles
    int sel = nt >> 2;
    int n0 = (nt & 3) * 256;
    int m0 = mt * 256;

    const bf16_t* gA = Xb + (size_t)sel * XMAT + (size_t)m0 * E_DIM;
    const bf16_t* gB = Weff + (size_t)sel * MAT + (size_t)n0 * E_DIM;
    const float*  bb = beff + sel * E_DIM;

    // double-buffered: A 2x(256x64) 64KB + B same = 128KB
    __shared__ __align__(16) bf16_t sA[2][256 * 64];
    __shared__ __align__(16) bf16_t sB[2][256 * 64];

    int tid  = threadIdx.x;
    int lane = tid & 63;
    int wid  = tid >> 6;
    int wr = wid >> 2;        // 0..1 : M interleave (rows m*32 + wr*16)
    int wc = wid & 3;         // 0..3 : N interleave (cols n*64 + wc*16)
    int cl = lane & 15;
    int rg = lane >> 4;
    int wr16cl = wr * 16 + cl;
    int wc16cl = wc * 16 + cl;

    // half-stage addressing: 128 rows x 64 cols bf16 = 16KB = 2 calls x 512thr x 16B
    // LDS linear dest; global source pre-swizzled col ^= (row&7)<<3 (16B granular)
    int c0 = tid, c1 = 512 + tid;
    int r0 = c0 >> 3, r1 = c1 >> 3;
    int go0 = r0 * E_DIM + (((c0 & 7) * 8) ^ ((r0 & 7) << 3));
    int go1 = r1 * E_DIM + (((c1 & 7) * 8) ^ ((r1 & 7) << 3));
    int ld0 = c0 * 8, ld1 = c1 * 8;

    // fragment k-offsets (swizzle dep = cl&7 only, since row&7 == cl&7)
    int koff0 = (rg * 8) ^ ((cl & 7) << 3);
    int koff1 = (32 + rg * 8) ^ ((cl & 7) << 3);

    f32x4 acc[8][4] = {};
    bf16x8 af[4][2], bq[2][2];

#define STAGE_A(kt, h, prt) do { \
    gload_lds16(gA + (size_t)((h) * 128) * E_DIM + (kt) * 64 + go0, &sA[prt][(h) * 8192 + ld0]); \
    gload_lds16(gA + (size_t)((h) * 128) * E_DIM + (kt) * 64 + go1, &sA[prt][(h) * 8192 + ld1]); } while (0)
#define STAGE_B(kt, h, prt) do { \
    gload_lds16(gB + (size_t)((h) * 128) * E_DIM + (kt) * 64 + go0, &sB[prt][(h) * 8192 + ld0]); \
    gload_lds16(gB + (size_t)((h) * 128) * E_DIM + (kt) * 64 + go1, &sB[prt][(h) * 8192 + ld1]); } while (0)
#define RD_A(p, mh) do { _Pragma("unroll") for (int m = 0; m < 4; ++m) { \
    af[m][0] = *(const bf16x8*)(&sA[p][((mh) * 128 + m * 32 + wr16cl) * 64 + koff0]); \
    af[m][1] = *(const bf16x8*)(&sA[p][((mh) * 128 + m * 32 + wr16cl) * 64 + koff1]); } } while (0)
#define RD_B(p, nh) do { _Pragma("unroll") for (int n = 0; n < 2; ++n) { \
    bq[n][0] = *(const bf16x8*)(&sB[p][((nh) * 128 + n * 64 + wc16cl) * 64 + koff0]); \
    bq[n][1] = *(const bf16x8*)(&sB[p][((nh) * 128 + n * 64 + wc16cl) * 64 + koff1]); } } while (0)
#define MM(mh, nh) do { __builtin_amdgcn_s_setprio(1); \
    _Pragma("unroll") for (int m = 0; m < 4; ++m) _Pragma("unroll") for (int n = 0; n < 2; ++n) { \
        acc[(mh) * 4 + m][(nh) * 2 + n] = __builtin_amdgcn_mfma_f32_16x16x32_bf16(af[m][0], bq[n][0], acc[(mh) * 4 + m][(nh) * 2 + n], 0, 0, 0); \
        acc[(mh) * 4 + m][(nh) * 2 + n] = __builtin_amdgcn_mfma_f32_16x16x32_bf16(af[m][1], bq[n][1], acc[(mh) * 4 + m][(nh) * 2 + n], 0, 0, 0); } \
    __builtin_amdgcn_s_setprio(0); } while (0)

    // prologue: stage tile 0 (order = steady-state: Ah0, Bh0, Bh1, Ah1)
    STAGE_A(0, 0, 0); STAGE_B(0, 0, 0); STAGE_B(0, 1, 0); STAGE_A(0, 1, 0);
    VMW(4);            // Ah0,Bh0 landed; Bh1,Ah1 may fly
    BAR();

#pragma unroll
    for (int t = 0; t < 16; ++t) {
        const int p = t & 1, pn = p ^ 1;
        // ---- q0: quadrant (mh0, nh0); stage Ah0(t+1)
        RD_A(p, 0); RD_B(p, 0);
        if (t < 15) { STAGE_A(t + 1, 0, pn); VMW(4); } else { VMW(2); }
        BAR();
        MM(0, 0);
        BAR();
        // ---- q1: (mh0, nh1); stage Bh0(t+1)
        RD_B(p, 1);
        if (t < 15) { STAGE_B(t + 1, 0, pn); VMW(4); } else { VMW(0); }
        BAR();
        MM(0, 1);
        BAR();
        // ---- q2: (mh1, nh1); stage Bh1(t+1); no wait needed
        RD_A(p, 1);
        if (t < 15) STAGE_B(t + 1, 1, pn);
        BAR();
        MM(1, 1);
        BAR();
        // ---- q3: (mh1, nh0); stage Ah1(t+1); wait guards next q0
        RD_B(p, 0);
        if (t < 15) { STAGE_A(t + 1, 1, pn); VMW(4); }
        BAR();
        MM(1, 0);
        BAR();
    }

    // epilogue: +bias, f32 store (out width = 2048)
#pragma unroll
    for (int mi = 0; mi < 8; ++mi) {
        int r = m0 + mi * 32 + wr * 16 + rg * 4;
#pragma unroll
        for (int n = 0; n < 4; ++n) {
            int ch = n0 + n * 64 + wc16cl;
            float bias = bb[ch];
            size_t gc = (size_t)sel * E_DIM + ch;
#pragma unroll
            for (int j = 0; j < 4; ++j)
                out[(size_t)(r + j) * (2 * E_DIM) + gc] = acc[mi][n][j] + bias;
        }
    }
#undef STAGE_A
#undef STAGE_B
#undef RD_A
#undef RD_B
#undef MM
}

// ---------------------------------------------------------------------------
extern "C" void kernel_launch(void* const* d_in, const int* in_sizes, int n_in,
                              void* d_out, int out_size, void* d_ws, size_t ws_size,
                              hipStream_t stream) {
    const float* text   = (const float*)d_in[0];
    const float* ecg    = (const float*)d_in[1];
    const float* Wqkv_a = (const float*)d_in[7];
    const float* bqkv_a = (const float*)d_in[8];
    const float* Wo_a   = (const float*)d_in[9];
    const float* bo_a   = (const float*)d_in[10];
    const float* Wqkv_b = (const float*)d_in[11];
    const float* bqkv_b = (const float*)d_in[12];
    const float* Wo_b   = (const float*)d_in[13];
    const float* bo_b   = (const float*)d_in[14];

    const size_t MAT  = (size_t)E_DIM * E_DIM;
    const size_t XMAT = (size_t)B_ROWS * E_DIM;
    bf16_t* WoB  = (bf16_t*)d_ws;                 // 4 MB
    bf16_t* WvT  = WoB + 2 * MAT;                 // 4 MB
    bf16_t* Weff = WvT + 2 * MAT;                 // 4 MB
    float*  beff = (float*)(Weff + 2 * MAT);      // 8 KB
    bf16_t* Xb   = (bf16_t*)(beff + 2 * E_DIM);   // 64 MB   (total ~76 MB)

    cvt_x2_k<<<4096, 256, 0, stream>>>(ecg, text, Xb);
    cvt_w2_k<<<2048, 256, 0, stream>>>(Wo_a, Wo_b, WoB);
    transpose_cvt2_k<<<512, 256, 0, stream>>>(Wqkv_a, Wqkv_b, WvT);
    fuse_gemm_k<<<128, 256, 0, stream>>>(WoB, WvT, Weff);
    fuse_bias2_k<<<2048, 64, 0, stream>>>(Wo_a, bqkv_a, bo_a, Wo_b, bqkv_b, bo_b, beff);
    main_gemm_256_k<<<512, 512, 0, stream>>>(Xb, Weff, beff, (float*)d_out);
}